// Round 1
// baseline (4116.225 us; speedup 1.0000x reference)
//
#include <hip/hip_runtime.h>
#include <math.h>

// Problem constants
#define NSEQ 4
#define BATCH 256
#define T 64
#define FIN 32
#define S 512

// Decomposition: 32 batch-groups x 8 rows, 8 S-slices x 64 dims -> 256 WGs
#define RPG 8       // rows per group
#define SLICES 8    // WGs per group (slice of S)
#define SW 64       // slice width
#define NT 256      // threads per WG
#define NWG 256

// Workspace layout (float element offsets). TBS = T*BATCH*S.
#define TBS 8388608ull
#define XW_OFF 0ull              // [T][B][S] x@Wx + bias, recomputed per lane
#define ST0_OFF TBS              // states ping  [T][B][S]
#define ST1_OFF (2ull * TBS)     // states pong  [T][B][S]
#define CTL_OFF (3ull * TBS)     // barrier counters: 32 groups x 32 uints
// total ws needed: 3*TBS*4 + 4096 bytes ~= 96.01 MiB

#define FLAG_MAGIC 0x13572468u

// Barrier among the SLICES WGs of one batch group. Device-scope counter,
// monotone target (8,16,24,...). Counter zeroed via init handshake: flag is
// harness-poisoned to 0xAAAAAAAA before every launch, so flag!=MAGIC until
// slice 0 has zeroed the counter.
__device__ __forceinline__ void group_barrier(unsigned* cnt, unsigned target) {
  __syncthreads();
  if (threadIdx.x == 0) {
    __threadfence();  // release: make our state stores visible device-wide
    __hip_atomic_fetch_add(cnt, 1u, __ATOMIC_RELAXED, __HIP_MEMORY_SCOPE_AGENT);
    while (__hip_atomic_load(cnt, __ATOMIC_RELAXED, __HIP_MEMORY_SCOPE_AGENT) < target) {
      __builtin_amdgcn_s_sleep(1);
    }
    __threadfence();  // acquire: invalidate L1 so we see peers' stores
  }
  __syncthreads();
}

extern "C" __global__ void __launch_bounds__(NT, 1)
rnn_persistent(const float* __restrict__ x,      // [4][256][64][32]
               const float* __restrict__ Wcell,  // [4][544][512]
               const float* __restrict__ bcell,  // [4][512]
               const float* __restrict__ Wcomb,  // [3][1024]
               const float* __restrict__ bcomb,  // [3]
               const float* __restrict__ Wout,   // [512]
               float* __restrict__ out,          // [1024] = [lane][batch]
               float* __restrict__ ws)
{
  const int wg  = blockIdx.x;
  const int g   = wg >> 3;       // batch group
  const int sl  = wg & 7;        // S-slice
  const int r0  = g * RPG;
  const int sb  = sl * SW;
  const int tid = threadIdx.x;

  // matmul mapping: thread owns s-pair (sb+2p, sb+2p+1) and k-chunk [kc*64, kc*64+64)
  const int p  = tid & 31;
  const int kc = tid >> 5;
  // staging mapping: row rs, 16 contiguous k starting at ks
  const int rs = tid >> 5;
  const int ks = (tid & 31) * 16;
  // reduce/XW mapping
  const int s_ = tid & 63;
  const int q4 = tid >> 6;

  __shared__ float h_lds[RPG * 516];   // gated hc rows, stride 516 (16B-aligned rows)
  __shared__ float red[8 * RPG * SW];  // k-chunk partials [kc][r][s]
  __shared__ float xw_lds[RPG * SW];   // staged x-part for this step
  __shared__ float wg_lds[2 * S];      // gate weights for current lane
  __shared__ float gbuf[NT];           // generic reduction buffer
  __shared__ float wbuf[RPG];          // gate values per row

  // ---- barrier init handshake ----
  unsigned* ctl = (unsigned*)(ws + CTL_OFF);
  unsigned* cnt = ctl + g * 32;
  unsigned* flg = cnt + 16;
  if (sl == 0 && tid == 0) {
    __hip_atomic_store(cnt, 0u, __ATOMIC_RELAXED, __HIP_MEMORY_SCOPE_AGENT);
    __threadfence();
    __hip_atomic_store(flg, FLAG_MAGIC, __ATOMIC_RELEASE, __HIP_MEMORY_SCOPE_AGENT);
  }
  if (tid == 0) {
    while (__hip_atomic_load(flg, __ATOMIC_ACQUIRE, __HIP_MEMORY_SCOPE_AGENT) != FLAG_MAGIC)
      __builtin_amdgcn_s_sleep(1);
  }
  __syncthreads();

  unsigned phase = 0;
  float2 U[64];  // recurrent weight slice: U[j] = Wc[32+kc*64+j][sb+2p .. +1] (128 VGPRs)

  for (int i = 0; i < NSEQ; ++i) {
    const float* Wc = Wcell + (size_t)i * (FIN + S) * S;

    // load U into registers (L2-resident after first group touches it)
    #pragma unroll
    for (int j = 0; j < 64; ++j) {
      U[j] = *(const float2*)(Wc + (size_t)(FIN + kc * 64 + j) * S + sb + 2 * p);
    }
    if (i > 0) {
      for (int t2 = tid; t2 < 2 * S; t2 += NT)
        wg_lds[t2] = Wcomb[(i - 1) * 2 * S + t2];
    }
    const float bg = (i > 0) ? bcomb[i - 1] : 0.0f;
    __syncthreads();

    // ---- XW precompute for this lane: xw[t][b][s] = x_t @ Wx + bc ----
    {
      float wxr[FIN];
      #pragma unroll
      for (int f = 0; f < FIN; ++f) wxr[f] = Wc[(size_t)f * S + sb + s_];
      const float bcv = bcell[i * S + sb + s_];
      for (int t = q4; t < T; t += 4) {
        for (int r = 0; r < RPG; ++r) {
          const float* xr = x + (((size_t)i * BATCH + (r0 + r)) * T + t) * FIN;
          float acc = 0.0f;
          #pragma unroll
          for (int f = 0; f < FIN; ++f) acc = fmaf(xr[f], wxr[f], acc);
          ws[XW_OFF + ((size_t)t * BATCH + (r0 + r)) * S + sb + s_] = acc + bcv;
        }
      }
    }
    __syncthreads();  // drains vmcnt -> XW visible to all threads of this WG

    float*       stc = ws + ((i & 1) ? ST1_OFF : ST0_OFF);  // this lane's states
    const float* stp = ws + ((i & 1) ? ST0_OFF : ST1_OFF);  // previous lane's states

    for (int t = 0; t < T; ++t) {
      // ---- stage: gate + combine -> hc rows into LDS ----
      float hva[16], pva[16];
      if (t > 0) {
        const float4* h4p = (const float4*)(stc + ((size_t)(t - 1) * BATCH + (r0 + rs)) * S + ks);
        #pragma unroll
        for (int j = 0; j < 4; ++j) {
          float4 v = h4p[j];
          hva[4*j+0] = v.x; hva[4*j+1] = v.y; hva[4*j+2] = v.z; hva[4*j+3] = v.w;
        }
      } else {
        #pragma unroll
        for (int j = 0; j < 16; ++j) hva[j] = 0.0f;
      }
      if (i > 0) {
        const float4* p4p = (const float4*)(stp + ((size_t)t * BATCH + (r0 + rs)) * S + ks);
        #pragma unroll
        for (int j = 0; j < 4; ++j) {
          float4 v = p4p[j];
          pva[4*j+0] = v.x; pva[4*j+1] = v.y; pva[4*j+2] = v.z; pva[4*j+3] = v.w;
        }
        float gp = 0.0f;
        #pragma unroll
        for (int j = 0; j < 16; ++j) {
          gp = fmaf(hva[j], wg_lds[ks + j], gp);
          gp = fmaf(pva[j], wg_lds[S + ks + j], gp);
        }
        gbuf[tid] = gp;
        __syncthreads();
        if (tid < RPG) {
          float ssum = 0.0f;
          for (int j = 0; j < 32; ++j) ssum += gbuf[tid * 32 + j];
          wbuf[tid] = 1.0f / (1.0f + expf(-(ssum + bg)));
        }
        __syncthreads();
        const float w = wbuf[rs], wi = 1.0f - w;
        #pragma unroll
        for (int j = 0; j < 16; ++j) hva[j] = w * hva[j] + wi * pva[j];
      }
      #pragma unroll
      for (int j = 0; j < 4; ++j) {
        *(float4*)&h_lds[rs * 516 + ks + 4 * j] =
            make_float4(hva[4*j], hva[4*j+1], hva[4*j+2], hva[4*j+3]);
      }
      // stage x-part for this step
      {
        const int rr = tid >> 6;
        xw_lds[rr * SW + s_]       = ws[XW_OFF + ((size_t)t * BATCH + r0 + rr) * S + sb + s_];
        xw_lds[(rr + 4) * SW + s_] = ws[XW_OFF + ((size_t)t * BATCH + r0 + rr + 4) * S + sb + s_];
      }
      __syncthreads();

      // ---- matvec: partials over this thread's k-chunk, s-pair, all 8 rows ----
      float accA[RPG], accB[RPG];
      #pragma unroll
      for (int r = 0; r < RPG; ++r) {
        const float* hrow = &h_lds[r * 516 + kc * 64];
        float ax = 0.f, ay = 0.f, az = 0.f, aw = 0.f;
        float bx = 0.f, by = 0.f, bz = 0.f, bw = 0.f;
        #pragma unroll
        for (int j = 0; j < 64; j += 4) {
          const float4 h4 = *(const float4*)(hrow + j);  // uniform-address broadcast
          ax = fmaf(h4.x, U[j    ].x, ax); bx = fmaf(h4.x, U[j    ].y, bx);
          ay = fmaf(h4.y, U[j + 1].x, ay); by = fmaf(h4.y, U[j + 1].y, by);
          az = fmaf(h4.z, U[j + 2].x, az); bz = fmaf(h4.z, U[j + 2].y, bz);
          aw = fmaf(h4.w, U[j + 3].x, aw); bw = fmaf(h4.w, U[j + 3].y, bw);
        }
        accA[r] = (ax + ay) + (az + aw);
        accB[r] = (bx + by) + (bz + bw);
      }
      #pragma unroll
      for (int r = 0; r < RPG; ++r) {
        *(float2*)&red[(kc * RPG + r) * SW + 2 * p] = make_float2(accA[r], accB[r]);
      }
      __syncthreads();

      // ---- reduce k-chunks + tanh + store state ----
      {
        const int rbase = tid >> 6;
        #pragma unroll
        for (int rr = 0; rr < 2; ++rr) {
          const int r = rbase + rr * 4;
          float sum = xw_lds[r * SW + s_];
          #pragma unroll
          for (int c = 0; c < 8; ++c) sum += red[(c * RPG + r) * SW + s_];
          const float hn = tanhf(sum);
          stc[((size_t)t * BATCH + r0 + r) * S + sb + s_] = hn;
        }
      }
      ++phase;
      group_barrier(cnt, (unsigned)SLICES * phase);
    }

    // ---- final output for this lane: out[i*256 + b] = h_T[b] . Wout ----
    if (sl == 0) {
      const int rr = tid >> 5;
      const int c  = tid & 31;
      const float* hrow = stc + ((size_t)(T - 1) * BATCH + r0 + rr) * S + c * 16;
      float acc = 0.0f;
      #pragma unroll
      for (int j = 0; j < 16; ++j) acc = fmaf(hrow[j], Wout[c * 16 + j], acc);
      gbuf[tid] = acc;
      __syncthreads();
      if (tid < RPG) {
        float ssum = 0.0f;
        for (int j = 0; j < 32; ++j) ssum += gbuf[tid * 32 + j];
        out[i * BATCH + r0 + tid] = ssum;
      }
      __syncthreads();
    }
  }
}

extern "C" void kernel_launch(void* const* d_in, const int* in_sizes, int n_in,
                              void* d_out, int out_size, void* d_ws, size_t ws_size,
                              hipStream_t stream) {
  (void)in_sizes; (void)n_in; (void)out_size; (void)ws_size;
  rnn_persistent<<<dim3(NWG), dim3(NT), 0, stream>>>(
      (const float*)d_in[0],   // inputs
      (const float*)d_in[1],   // W_cell
      (const float*)d_in[2],   // b_cell
      (const float*)d_in[3],   // W_comb
      (const float*)d_in[4],   // b_comb
      (const float*)d_in[5],   // W_out
      (float*)d_out,
      (float*)d_ws);
}

// Round 2
// 2185.685 us; speedup vs baseline: 1.8833x; 1.8833x over previous
//
#include <hip/hip_runtime.h>
#include <math.h>

// Problem constants
#define NSEQ 4
#define BATCH 256
#define T 64
#define FIN 32
#define S 512

// Decomposition: 32 batch-groups x 8 rows, 8 S-slices x 64 dims -> 256 WGs
#define RPG 8       // rows per group
#define SLICES 8    // WGs per group (slice of S)
#define SW 64       // slice width
#define NT 256      // threads per WG
#define NWG 256

// Workspace layout (float element offsets). TBS = T*BATCH*S.
#define TBS 8388608ull
#define XW_OFF 0ull              // [T][B][S] x@Wx + bias, recomputed per lane
#define ST0_OFF TBS              // states ping  [T][B][S]
#define ST1_OFF (2ull * TBS)     // states pong  [T][B][S]
#define CTL_OFF (3ull * TBS)     // barrier counters: 32 groups x 32 uints
// total ws needed: 3*TBS*4 + 4096 bytes ~= 96.01 MiB

#define FLAG_MAGIC 0x13572468u

// ---- coherent (cross-XCD) scalar access helpers -------------------------
// Agent-scope relaxed atomics: compiler sets the sc bits so these bypass the
// non-coherent L1/per-XCD-L2 and hit the Infinity Cache (the agent coherence
// point). No cache-wide maintenance (wbl2/inv) is ever emitted for relaxed.
__device__ __forceinline__ float cload(const float* p) {
  return __hip_atomic_load(p, __ATOMIC_RELAXED, __HIP_MEMORY_SCOPE_AGENT);
}
__device__ __forceinline__ void cstore(float* p, float v) {
  __hip_atomic_store(p, v, __ATOMIC_RELAXED, __HIP_MEMORY_SCOPE_AGENT);
}

// Barrier among the SLICES WGs of one batch group. All state stores are
// individually coherent (cstore), so release = s_waitcnt vmcnt(0) only —
// NO buffer_wbl2 / buffer_inv (that was the R1 disaster: full L2
// writeback+invalidate per step = 1 GB of HBM churn + cold-miss latency).
__device__ __forceinline__ void group_barrier(unsigned* cnt, unsigned target) {
  __syncthreads();
  if (threadIdx.x == 0) {
    asm volatile("s_waitcnt vmcnt(0)" ::: "memory");  // coherent stores reached MALL
    __hip_atomic_fetch_add(cnt, 1u, __ATOMIC_RELAXED, __HIP_MEMORY_SCOPE_AGENT);
    while (__hip_atomic_load(cnt, __ATOMIC_RELAXED, __HIP_MEMORY_SCOPE_AGENT) < target) {
      __builtin_amdgcn_s_sleep(1);
    }
    asm volatile("" ::: "memory");  // no hoisting of state loads above the poll
  }
  __syncthreads();
}

extern "C" __global__ void __launch_bounds__(NT, 1)
rnn_persistent(const float* __restrict__ x,      // [4][256][64][32]
               const float* __restrict__ Wcell,  // [4][544][512]
               const float* __restrict__ bcell,  // [4][512]
               const float* __restrict__ Wcomb,  // [3][1024]
               const float* __restrict__ bcomb,  // [3]
               const float* __restrict__ Wout,   // [512]
               float* __restrict__ out,          // [1024] = [lane][batch]
               float* __restrict__ ws)
{
  const int wg  = blockIdx.x;
  const int g   = wg >> 3;       // batch group
  const int sl  = wg & 7;        // S-slice
  const int r0  = g * RPG;
  const int sb  = sl * SW;
  const int tid = threadIdx.x;

  // matmul mapping: thread owns s-pair (sb+2p, sb+2p+1) and k-chunk [kc*64, kc*64+64)
  const int p  = tid & 31;
  const int kc = tid >> 5;
  // staging mapping: row rs = tid&7, 16 contiguous k starting at ks.
  // (R1 had rs=tid>>5, ks=(tid&31)*16 -> 16-float lane stride -> 16-way LDS
  //  bank conflicts on the h_lds b128 writes. This mapping is 2-way = free.)
  const int rs = tid & 7;
  const int ks = (tid >> 3) * 16;
  // reduce/XW mapping
  const int s_ = tid & 63;
  const int q4 = tid >> 6;

  __shared__ float h_lds[RPG * 516];   // gated hc rows, stride 516 (16B-aligned rows)
  __shared__ float red[8 * RPG * SW];  // k-chunk partials [kc][r][s]
  __shared__ float xw_lds[RPG * SW];   // staged x-part for this step
  __shared__ float wg_lds[2 * S];      // gate weights for current lane
  __shared__ float gbuf[NT];           // generic reduction buffer
  __shared__ float wbuf[RPG];          // gate values per row

  // ---- barrier init handshake ----
  unsigned* ctl = (unsigned*)(ws + CTL_OFF);
  unsigned* cnt = ctl + g * 32;
  unsigned* flg = cnt + 16;
  if (sl == 0 && tid == 0) {
    __hip_atomic_store(cnt, 0u, __ATOMIC_RELAXED, __HIP_MEMORY_SCOPE_AGENT);
    __hip_atomic_store(flg, FLAG_MAGIC, __ATOMIC_RELEASE, __HIP_MEMORY_SCOPE_AGENT);
  }
  if (tid == 0) {
    while (__hip_atomic_load(flg, __ATOMIC_ACQUIRE, __HIP_MEMORY_SCOPE_AGENT) != FLAG_MAGIC)
      __builtin_amdgcn_s_sleep(1);
  }
  __syncthreads();

  unsigned phase = 0;
  float2 U[64];  // recurrent weight slice: U[j] = Wc[32+kc*64+j][sb+2p .. +1] (128 VGPRs)

  for (int i = 0; i < NSEQ; ++i) {
    const float* Wc = Wcell + (size_t)i * (FIN + S) * S;

    // load U into registers (L2-resident after first group touches it)
    #pragma unroll
    for (int j = 0; j < 64; ++j) {
      U[j] = *(const float2*)(Wc + (size_t)(FIN + kc * 64 + j) * S + sb + 2 * p);
    }
    if (i > 0) {
      for (int t2 = tid; t2 < 2 * S; t2 += NT)
        wg_lds[t2] = Wcomb[(i - 1) * 2 * S + t2];
    }
    const float bg = (i > 0) ? bcomb[i - 1] : 0.0f;
    __syncthreads();

    // ---- XW precompute for this lane: xw[t][b][s] = x_t @ Wx + bc ----
    // Same-WG producer/consumer only -> plain (L2-cached) stores/loads.
    {
      float wxr[FIN];
      #pragma unroll
      for (int f = 0; f < FIN; ++f) wxr[f] = Wc[(size_t)f * S + sb + s_];
      const float bcv = bcell[i * S + sb + s_];
      for (int t = q4; t < T; t += 4) {
        for (int r = 0; r < RPG; ++r) {
          const float* xr = x + (((size_t)i * BATCH + (r0 + r)) * T + t) * FIN;
          float acc = 0.0f;
          #pragma unroll
          for (int f = 0; f < FIN; ++f) acc = fmaf(xr[f], wxr[f], acc);
          ws[XW_OFF + ((size_t)t * BATCH + (r0 + r)) * S + sb + s_] = acc + bcv;
        }
      }
    }
    __syncthreads();

    float*       stc = ws + ((i & 1) ? ST1_OFF : ST0_OFF);  // this lane's states
    const float* stp = ws + ((i & 1) ? ST0_OFF : ST1_OFF);  // previous lane's states

    for (int t = 0; t < T; ++t) {
      // ---- stage: gate + combine -> hc rows into LDS ----
      float hva[16], pva[16];
      if (t > 0) {
        const float* hp = stc + ((size_t)(t - 1) * BATCH + (r0 + rs)) * S + ks;
        #pragma unroll
        for (int j = 0; j < 16; ++j) hva[j] = cload(hp + j);  // 16 indep MALL loads
      } else {
        #pragma unroll
        for (int j = 0; j < 16; ++j) hva[j] = 0.0f;
      }
      if (i > 0) {
        const float* pp = stp + ((size_t)t * BATCH + (r0 + rs)) * S + ks;
        #pragma unroll
        for (int j = 0; j < 16; ++j) pva[j] = cload(pp + j);
        float gp = 0.0f;
        #pragma unroll
        for (int j = 0; j < 16; ++j) {
          gp = fmaf(hva[j], wg_lds[ks + j], gp);
          gp = fmaf(pva[j], wg_lds[S + ks + j], gp);
        }
        gbuf[tid] = gp;
        __syncthreads();
        if (tid < RPG) {
          float ssum = 0.0f;
          for (int j = 0; j < 32; ++j) ssum += gbuf[tid + 8 * j];  // row = tid&7 mapping
          wbuf[tid] = 1.0f / (1.0f + expf(-(ssum + bg)));
        }
        __syncthreads();
        const float w = wbuf[rs], wi = 1.0f - w;
        #pragma unroll
        for (int j = 0; j < 16; ++j) hva[j] = w * hva[j] + wi * pva[j];
      }
      #pragma unroll
      for (int j = 0; j < 4; ++j) {
        *(float4*)&h_lds[rs * 516 + ks + 4 * j] =
            make_float4(hva[4*j], hva[4*j+1], hva[4*j+2], hva[4*j+3]);
      }
      // stage x-part for this step
      {
        const int rr = tid >> 6;
        xw_lds[rr * SW + s_]       = ws[XW_OFF + ((size_t)t * BATCH + r0 + rr) * S + sb + s_];
        xw_lds[(rr + 4) * SW + s_] = ws[XW_OFF + ((size_t)t * BATCH + r0 + rr + 4) * S + sb + s_];
      }
      __syncthreads();

      // ---- matvec: partials over this thread's k-chunk, s-pair, all 8 rows ----
      float accA[RPG], accB[RPG];
      #pragma unroll
      for (int r = 0; r < RPG; ++r) {
        const float* hrow = &h_lds[r * 516 + kc * 64];
        float ax = 0.f, ay = 0.f, az = 0.f, aw = 0.f;
        float bx = 0.f, by = 0.f, bz = 0.f, bw = 0.f;
        #pragma unroll
        for (int j = 0; j < 64; j += 4) {
          const float4 h4 = *(const float4*)(hrow + j);  // uniform-address broadcast
          ax = fmaf(h4.x, U[j    ].x, ax); bx = fmaf(h4.x, U[j    ].y, bx);
          ay = fmaf(h4.y, U[j + 1].x, ay); by = fmaf(h4.y, U[j + 1].y, by);
          az = fmaf(h4.z, U[j + 2].x, az); bz = fmaf(h4.z, U[j + 2].y, bz);
          aw = fmaf(h4.w, U[j + 3].x, aw); bw = fmaf(h4.w, U[j + 3].y, bw);
        }
        accA[r] = (ax + ay) + (az + aw);
        accB[r] = (bx + by) + (bz + bw);
      }
      #pragma unroll
      for (int r = 0; r < RPG; ++r) {
        *(float2*)&red[(kc * RPG + r) * SW + 2 * p] = make_float2(accA[r], accB[r]);
      }
      __syncthreads();

      // ---- reduce k-chunks + tanh + coherent state store ----
      {
        const int rbase = tid >> 6;
        #pragma unroll
        for (int rr = 0; rr < 2; ++rr) {
          const int r = rbase + rr * 4;
          float sum = xw_lds[r * SW + s_];
          #pragma unroll
          for (int c = 0; c < 8; ++c) sum += red[(c * RPG + r) * SW + s_];
          const float hn = tanhf(sum);
          cstore(stc + ((size_t)t * BATCH + r0 + r) * S + sb + s_, hn);
        }
      }
      ++phase;
      group_barrier(cnt, (unsigned)SLICES * phase);
    }

    // ---- final output for this lane: out[i*256 + b] = h_T[b] . Wout ----
    if (sl == 0) {
      const int rr = tid >> 5;
      const int c  = tid & 31;
      const float* hrow = stc + ((size_t)(T - 1) * BATCH + r0 + rr) * S + c * 16;
      float acc = 0.0f;
      #pragma unroll
      for (int j = 0; j < 16; ++j) acc = fmaf(cload(hrow + j), Wout[c * 16 + j], acc);
      gbuf[tid] = acc;
      __syncthreads();
      if (tid < RPG) {
        float ssum = 0.0f;
        for (int j = 0; j < 32; ++j) ssum += gbuf[tid * 32 + j];
        out[i * BATCH + r0 + tid] = ssum;
      }
      __syncthreads();
    }
  }
}

extern "C" void kernel_launch(void* const* d_in, const int* in_sizes, int n_in,
                              void* d_out, int out_size, void* d_ws, size_t ws_size,
                              hipStream_t stream) {
  (void)in_sizes; (void)n_in; (void)out_size; (void)ws_size;
  rnn_persistent<<<dim3(NWG), dim3(NT), 0, stream>>>(
      (const float*)d_in[0],   // inputs
      (const float*)d_in[1],   // W_cell
      (const float*)d_in[2],   // b_cell
      (const float*)d_in[3],   // b_comb? no: W_comb
      (const float*)d_in[4],   // b_comb
      (const float*)d_in[5],   // W_out
      (float*)d_out,
      (float*)d_ws);
}